// Round 1
// baseline (339.265 us; speedup 1.0000x reference)
//
#include <hip/hip_runtime.h>

typedef __attribute__((ext_vector_type(8))) short short8;
typedef __attribute__((ext_vector_type(4))) float f32x4;

#define B_ 2
#define S_ 2048
#define D_ 1024
#define H_ 16
#define DK_ 64

__device__ __forceinline__ unsigned short f2bf(float f) {
  union { float f; unsigned u; } x; x.f = f;
  unsigned r = x.u + 0x7FFFu + ((x.u >> 16) & 1u);
  return (unsigned short)(r >> 16);
}
__device__ __forceinline__ float bf2f(unsigned short h) {
  union { unsigned u; float f; } x; x.u = ((unsigned)h) << 16;
  return x.f;
}

__global__ __launch_bounds__(256) void cvt_kernel(const float* __restrict__ in,
                                                  unsigned short* __restrict__ out, int n) {
  int i = (blockIdx.x * 256 + threadIdx.x) * 4;
  if (i >= n) return;
  float4 v = *reinterpret_cast<const float4*>(in + i);
  ushort4 o;
  o.x = f2bf(v.x); o.y = f2bf(v.y); o.z = f2bf(v.z); o.w = f2bf(v.w);
  *reinterpret_cast<ushort4*>(out + i) = o;
}

__global__ __launch_bounds__(256) void rs_kernel(const float* __restrict__ reaches,
                                                 float* __restrict__ rs) {
  int b = blockIdx.x, t = threadIdx.x;
  float s = 0.f;
  for (int i = t; i < S_; i += 256) s += reaches[b * S_ + i];
  for (int o = 32; o > 0; o >>= 1) s += __shfl_down(s, o, 64);
  __shared__ float tmp[4];
  if ((t & 63) == 0) tmp[t >> 6] = s;
  __syncthreads();
  if (t == 0) rs[b] = tmp[0] + tmp[1] + tmp[2] + tmp[3];
}

// C[r][c] = sum_k A[r][k] * Bt[c][k]   (A: [M][K] bf16, Bt: [N][K] bf16, both row-major)
// mode 0: write bf16 head-split [B,H,S,DK] to outH ; mode 1: write fp32 row-major to outF
#define LDAB 40
__global__ __launch_bounds__(256) void gemm_bt(const unsigned short* __restrict__ A,
                                               const unsigned short* __restrict__ Bt,
                                               float* __restrict__ outF,
                                               unsigned short* __restrict__ outH,
                                               int M, int N, int K, int mode) {
  __shared__ unsigned short lA[128 * LDAB];
  __shared__ unsigned short lB[128 * LDAB];
  const int tid = threadIdx.x;
  const int nbn = N >> 7;
  const int bn = blockIdx.x % nbn, bm = blockIdx.x / nbn;
  const int w = tid >> 6, lane = tid & 63;
  const int wr = (w >> 1) * 64, wc = (w & 1) * 64;
  const int lr = lane & 15, lg = lane >> 4;

  f32x4 acc[4][4];
#pragma unroll
  for (int i = 0; i < 4; ++i)
#pragma unroll
    for (int j = 0; j < 4; ++j) acc[i][j] = (f32x4){0.f, 0.f, 0.f, 0.f};

  const int r0 = tid >> 2, e8 = (tid & 3) * 8;
  for (int kt = 0; kt < K; kt += 32) {
#pragma unroll
    for (int half = 0; half < 2; ++half) {
      int row = r0 + half * 64;
      *reinterpret_cast<short8*>(&lA[row * LDAB + e8]) =
          *reinterpret_cast<const short8*>(&A[(size_t)(bm * 128 + row) * K + kt + e8]);
      *reinterpret_cast<short8*>(&lB[row * LDAB + e8]) =
          *reinterpret_cast<const short8*>(&Bt[(size_t)(bn * 128 + row) * K + kt + e8]);
    }
    __syncthreads();
    short8 af[4], bfr[4];
#pragma unroll
    for (int i = 0; i < 4; ++i)
      af[i] = *reinterpret_cast<const short8*>(&lA[(wr + i * 16 + lr) * LDAB + lg * 8]);
#pragma unroll
    for (int j = 0; j < 4; ++j)
      bfr[j] = *reinterpret_cast<const short8*>(&lB[(wc + j * 16 + lr) * LDAB + lg * 8]);
#pragma unroll
    for (int i = 0; i < 4; ++i)
#pragma unroll
      for (int j = 0; j < 4; ++j)
        acc[i][j] = __builtin_amdgcn_mfma_f32_16x16x32_bf16(af[i], bfr[j], acc[i][j], 0, 0, 0);
    __syncthreads();
  }
#pragma unroll
  for (int i = 0; i < 4; ++i)
#pragma unroll
    for (int j = 0; j < 4; ++j)
#pragma unroll
      for (int ii = 0; ii < 4; ++ii) {
        int r = bm * 128 + wr + i * 16 + lg * 4 + ii;
        int c = bn * 128 + wc + j * 16 + lr;
        float v = acc[i][j][ii];
        if (mode == 0) {
          int b = r >> 11, s = r & (S_ - 1), h = c >> 6, dk = c & 63;
          outH[(((size_t)(b * H_ + h) * S_ + s) * DK_) + dk] = f2bf(v);
        } else {
          outF[(size_t)r * N + c] = v;
        }
      }
}

// One block = 64 query rows of one (b,h). Online softmax over 32 k-tiles of 64.
__global__ __launch_bounds__(256) void attn_kernel(const unsigned short* __restrict__ Qh,
                                                   const unsigned short* __restrict__ Kh,
                                                   const unsigned short* __restrict__ Vh,
                                                   const float* __restrict__ reaches,
                                                   const float* __restrict__ rsum,
                                                   unsigned short* __restrict__ concat) {
  __shared__ unsigned short lQ[64 * 72];
  __shared__ unsigned short lK[64 * 72];
  __shared__ unsigned short vT[64 * 72];   // vT[d][k] = V[k][d]
  __shared__ unsigned short pw[64 * 72];   // weighted probs bf16
  __shared__ float sS[64 * 68];
  __shared__ float rowScale[64];
  __shared__ float lSum[64];
  __shared__ float reachT[64];

  const int tid = threadIdx.x;
  const int qt = blockIdx.x & 31;
  const int bh = blockIdx.x >> 5;
  const int b = bh >> 4, h = bh & 15;
  const size_t base = (size_t)bh * S_ * DK_;

  const int w = tid >> 6, lane = tid & 63;
  const int lr = lane & 15, lg = lane >> 4;

  for (int c = tid; c < 512; c += 256) {
    int row = c >> 3, e8 = (c & 7) * 8;
    *reinterpret_cast<short8*>(&lQ[row * 72 + e8]) =
        *reinterpret_cast<const short8*>(&Qh[base + (size_t)(qt * 64 + row) * 64 + e8]);
  }

  const int sr = tid >> 2, ssub = tid & 3;
  const int qg_sr = qt * 64 + sr;
  float m_run = -1e30f, l_run = 0.f;
  f32x4 acc[4];
#pragma unroll
  for (int c4 = 0; c4 < 4; ++c4) acc[c4] = (f32x4){0.f, 0.f, 0.f, 0.f};

  for (int kt = 0; kt < 32; ++kt) {
    __syncthreads();  // prev PV done (and Q staged on first iter)
    for (int c = tid; c < 512; c += 256) {
      int row = c >> 3, e8 = (c & 7) * 8;
      *reinterpret_cast<short8*>(&lK[row * 72 + e8]) =
          *reinterpret_cast<const short8*>(&Kh[base + (size_t)(kt * 64 + row) * 64 + e8]);
      short8 vv = *reinterpret_cast<const short8*>(&Vh[base + (size_t)(kt * 64 + row) * 64 + e8]);
#pragma unroll
      for (int j = 0; j < 8; ++j) vT[(e8 + j) * 72 + row] = (unsigned short)vv[j];
    }
    if (tid < 64) reachT[tid] = reaches[b * S_ + kt * 64 + tid];
    __syncthreads();

    // S = Q K^T / 8  -> sS (wave w owns q rows [16w,16w+16))
    f32x4 sf[4];
#pragma unroll
    for (int c4 = 0; c4 < 4; ++c4) sf[c4] = (f32x4){0.f, 0.f, 0.f, 0.f};
#pragma unroll
    for (int kk = 0; kk < 2; ++kk) {
      short8 a = *reinterpret_cast<const short8*>(&lQ[(w * 16 + lr) * 72 + kk * 32 + lg * 8]);
#pragma unroll
      for (int c4 = 0; c4 < 4; ++c4) {
        short8 bb = *reinterpret_cast<const short8*>(&lK[(c4 * 16 + lr) * 72 + kk * 32 + lg * 8]);
        sf[c4] = __builtin_amdgcn_mfma_f32_16x16x32_bf16(a, bb, sf[c4], 0, 0, 0);
      }
    }
#pragma unroll
    for (int c4 = 0; c4 < 4; ++c4)
#pragma unroll
      for (int ii = 0; ii < 4; ++ii)
        sS[(w * 16 + lg * 4 + ii) * 68 + c4 * 16 + lr] = sf[c4][ii] * 0.125f;
    __syncthreads();

    // online softmax: thread -> row sr, k-segment [16*ssub, +16)
    float vals[16] __attribute__((aligned(16)));
    {
      float4* vp = reinterpret_cast<float4*>(vals);
      const float4* rp = reinterpret_cast<const float4*>(&sS[sr * 68 + ssub * 16]);
      vp[0] = rp[0]; vp[1] = rp[1]; vp[2] = rp[2]; vp[3] = rp[3];
    }
    float mx = vals[0];
#pragma unroll
    for (int j = 1; j < 16; ++j) mx = fmaxf(mx, vals[j]);
    mx = fmaxf(mx, __shfl_xor(mx, 1, 64));
    mx = fmaxf(mx, __shfl_xor(mx, 2, 64));
    float m_new = fmaxf(m_run, mx);
    float psum = 0.f;
#pragma unroll
    for (int j = 0; j < 16; ++j) { vals[j] = __expf(vals[j] - m_new); psum += vals[j]; }
    psum += __shfl_xor(psum, 1, 64);
    psum += __shfl_xor(psum, 2, 64);
    float alpha = __expf(m_run - m_new);
    l_run = l_run * alpha + psum;
    m_run = m_new;
    if (ssub == 0) rowScale[sr] = alpha;
#pragma unroll
    for (int j = 0; j < 16; j += 2) {
      int kg = kt * 64 + ssub * 16 + j;
      float w0 = reachT[ssub * 16 + j];
      float w1 = reachT[ssub * 16 + j + 1];
      if (kg == qg_sr) w0 *= (1.0f - 0.999999f);
      if (kg + 1 == qg_sr) w1 *= (1.0f - 0.999999f);
      unsigned p0 = f2bf(vals[j] * w0), p1 = f2bf(vals[j + 1] * w1);
      *reinterpret_cast<unsigned*>(&pw[sr * 72 + ssub * 16 + j]) = p0 | (p1 << 16);
    }
    __syncthreads();

    // PV: rescale acc, then acc += pw @ V
    float scl[4];
#pragma unroll
    for (int ii = 0; ii < 4; ++ii) scl[ii] = rowScale[w * 16 + lg * 4 + ii];
#pragma unroll
    for (int c4 = 0; c4 < 4; ++c4)
#pragma unroll
      for (int ii = 0; ii < 4; ++ii) acc[c4][ii] *= scl[ii];
#pragma unroll
    for (int kk = 0; kk < 2; ++kk) {
      short8 a = *reinterpret_cast<const short8*>(&pw[(w * 16 + lr) * 72 + kk * 32 + lg * 8]);
#pragma unroll
      for (int c4 = 0; c4 < 4; ++c4) {
        short8 bb = *reinterpret_cast<const short8*>(&vT[(c4 * 16 + lr) * 72 + kk * 32 + lg * 8]);
        acc[c4] = __builtin_amdgcn_mfma_f32_16x16x32_bf16(a, bb, acc[c4], 0, 0, 0);
      }
    }
  }
  __syncthreads();
  if (ssub == 0) lSum[sr] = l_run;
  __syncthreads();

  const float rb = rsum[b];
#pragma unroll
  for (int c4 = 0; c4 < 4; ++c4)
#pragma unroll
    for (int ii = 0; ii < 4; ++ii) {
      int qloc = w * 16 + lg * 4 + ii;
      int qg = qt * 64 + qloc;
      int d = c4 * 16 + lr;
      float pv = acc[c4][ii] / lSum[qloc];
      float vhv = bf2f(Vh[base + (size_t)qg * 64 + d]);
      float rq = reaches[b * S_ + qg];
      float contrib = (rb - rq) / (rb + 1e-9f) * (1.f - rq) * 100.f;
      float o = (vhv - pv) * contrib;
      concat[((size_t)(b * S_ + qg)) * D_ + h * 64 + d] = f2bf(o);
    }
}

extern "C" void kernel_launch(void* const* d_in, const int* in_sizes, int n_in,
                              void* d_out, int out_size, void* d_ws, size_t ws_size,
                              hipStream_t stream) {
  const float* q = (const float*)d_in[0];
  const float* k = (const float*)d_in[1];
  const float* v = (const float*)d_in[2];
  const float* reaches = (const float*)d_in[3];
  const float* Wq = (const float*)d_in[4];
  const float* Wk = (const float*)d_in[5];
  const float* Wv = (const float*)d_in[6];
  const float* Wo = (const float*)d_in[7];

  const size_t NQKV = (size_t)B_ * S_ * D_;   // 4194304
  const size_t NW = (size_t)D_ * D_;          // 1048576

  unsigned short* q_bf = (unsigned short*)d_ws;
  unsigned short* k_bf = q_bf + NQKV;
  unsigned short* v_bf = k_bf + NQKV;
  unsigned short* Wq_bf = v_bf + NQKV;
  unsigned short* Wk_bf = Wq_bf + NW;
  unsigned short* Wv_bf = Wk_bf + NW;
  unsigned short* Wo_bf = Wv_bf + NW;
  unsigned short* Qh = Wo_bf + NW;
  unsigned short* Kh = Qh + NQKV;
  unsigned short* Vh = Kh + NQKV;
  unsigned short* concat = Vh + NQKV;
  float* rs = (float*)(concat + NQKV);

  cvt_kernel<<<NQKV / 1024, 256, 0, stream>>>(q, q_bf, (int)NQKV);
  cvt_kernel<<<NQKV / 1024, 256, 0, stream>>>(k, k_bf, (int)NQKV);
  cvt_kernel<<<NQKV / 1024, 256, 0, stream>>>(v, v_bf, (int)NQKV);
  cvt_kernel<<<NW / 1024, 256, 0, stream>>>(Wq, Wq_bf, (int)NW);
  cvt_kernel<<<NW / 1024, 256, 0, stream>>>(Wk, Wk_bf, (int)NW);
  cvt_kernel<<<NW / 1024, 256, 0, stream>>>(Wv, Wv_bf, (int)NW);
  cvt_kernel<<<NW / 1024, 256, 0, stream>>>(Wo, Wo_bf, (int)NW);
  rs_kernel<<<B_, 256, 0, stream>>>(reaches, rs);

  const int M = B_ * S_;  // 4096
  gemm_bt<<<(M / 128) * (D_ / 128), 256, 0, stream>>>(q_bf, Wq_bf, nullptr, Qh, M, D_, D_, 0);
  gemm_bt<<<(M / 128) * (D_ / 128), 256, 0, stream>>>(k_bf, Wk_bf, nullptr, Kh, M, D_, D_, 0);
  gemm_bt<<<(M / 128) * (D_ / 128), 256, 0, stream>>>(v_bf, Wv_bf, nullptr, Vh, M, D_, D_, 0);

  attn_kernel<<<B_ * H_ * (S_ / 64), 256, 0, stream>>>(Qh, Kh, Vh, reaches, rs, concat);

  gemm_bt<<<(M / 128) * (D_ / 128), 256, 0, stream>>>(concat, Wo_bf, (float*)d_out, nullptr, M, D_, D_, 1);
}

// Round 2
// 265.467 us; speedup vs baseline: 1.2780x; 1.2780x over previous
//
#include <hip/hip_runtime.h>

typedef __attribute__((ext_vector_type(8))) short short8;
typedef __attribute__((ext_vector_type(4))) float f32x4;

#define B_ 2
#define S_ 2048
#define D_ 1024
#define H_ 16
#define DK_ 64

__device__ __forceinline__ unsigned short f2bf(float f) {
  union { float f; unsigned u; } x; x.f = f;
  unsigned r = x.u + 0x7FFFu + ((x.u >> 16) & 1u);
  return (unsigned short)(r >> 16);
}
__device__ __forceinline__ float bf2f(unsigned short h) {
  union { unsigned u; float f; } x; x.u = ((unsigned)h) << 16;
  return x.f;
}

__global__ __launch_bounds__(256) void cvt3_kernel(const float* __restrict__ a,
                                                   const float* __restrict__ b,
                                                   const float* __restrict__ c,
                                                   unsigned short* __restrict__ oa,
                                                   unsigned short* __restrict__ ob,
                                                   unsigned short* __restrict__ oc) {
  const float* in; unsigned short* out;
  if (blockIdx.y == 0) { in = a; out = oa; }
  else if (blockIdx.y == 1) { in = b; out = ob; }
  else { in = c; out = oc; }
  int i = (blockIdx.x * 256 + threadIdx.x) * 4;
  float4 v = *reinterpret_cast<const float4*>(in + i);
  ushort4 o;
  o.x = f2bf(v.x); o.y = f2bf(v.y); o.z = f2bf(v.z); o.w = f2bf(v.w);
  *reinterpret_cast<ushort4*>(out + i) = o;
}

__global__ __launch_bounds__(256) void cvt4_kernel(const float* __restrict__ a,
                                                   const float* __restrict__ b,
                                                   const float* __restrict__ c,
                                                   const float* __restrict__ d,
                                                   unsigned short* __restrict__ oa,
                                                   unsigned short* __restrict__ ob,
                                                   unsigned short* __restrict__ oc,
                                                   unsigned short* __restrict__ od) {
  const float* in; unsigned short* out;
  if (blockIdx.y == 0) { in = a; out = oa; }
  else if (blockIdx.y == 1) { in = b; out = ob; }
  else if (blockIdx.y == 2) { in = c; out = oc; }
  else { in = d; out = od; }
  int i = (blockIdx.x * 256 + threadIdx.x) * 4;
  float4 v = *reinterpret_cast<const float4*>(in + i);
  ushort4 o;
  o.x = f2bf(v.x); o.y = f2bf(v.y); o.z = f2bf(v.z); o.w = f2bf(v.w);
  *reinterpret_cast<ushort4*>(out + i) = o;
}

__global__ __launch_bounds__(256) void rs_kernel(const float* __restrict__ reaches,
                                                 float* __restrict__ rs) {
  int b = blockIdx.x, t = threadIdx.x;
  float s = 0.f;
  for (int i = t; i < S_; i += 256) s += reaches[b * S_ + i];
  for (int o = 32; o > 0; o >>= 1) s += __shfl_down(s, o, 64);
  __shared__ float tmp[4];
  if ((t & 63) == 0) tmp[t >> 6] = s;
  __syncthreads();
  if (t == 0) rs[b] = tmp[0] + tmp[1] + tmp[2] + tmp[3];
}

// C[r][c] = oscale * sum_k A[r][k]*Bt[c][k]
// mode 0: bf16 head-split [B,H,S,DK] -> outH ; mode 1: fp32 row-major -> outF
#define LDAB 40
__global__ __launch_bounds__(256) void gemm_bt(const unsigned short* __restrict__ A,
                                               const unsigned short* __restrict__ Bt,
                                               float* __restrict__ outF,
                                               unsigned short* __restrict__ outH,
                                               int M, int N, int K, int mode, float oscale) {
  __shared__ unsigned short lA[128 * LDAB];
  __shared__ unsigned short lB[128 * LDAB];
  const int tid = threadIdx.x;
  const int nbn = N >> 7;
  const int bn = blockIdx.x % nbn, bm = blockIdx.x / nbn;
  const int w = tid >> 6, lane = tid & 63;
  const int wr = (w >> 1) * 64, wc = (w & 1) * 64;
  const int lr = lane & 15, lg = lane >> 4;

  f32x4 acc[4][4];
#pragma unroll
  for (int i = 0; i < 4; ++i)
#pragma unroll
    for (int j = 0; j < 4; ++j) acc[i][j] = (f32x4){0.f, 0.f, 0.f, 0.f};

  const int r0 = tid >> 2, e8 = (tid & 3) * 8;
  for (int kt = 0; kt < K; kt += 32) {
#pragma unroll
    for (int half = 0; half < 2; ++half) {
      int row = r0 + half * 64;
      *reinterpret_cast<short8*>(&lA[row * LDAB + e8]) =
          *reinterpret_cast<const short8*>(&A[(size_t)(bm * 128 + row) * K + kt + e8]);
      *reinterpret_cast<short8*>(&lB[row * LDAB + e8]) =
          *reinterpret_cast<const short8*>(&Bt[(size_t)(bn * 128 + row) * K + kt + e8]);
    }
    __syncthreads();
    short8 af[4], bfr[4];
#pragma unroll
    for (int i = 0; i < 4; ++i)
      af[i] = *reinterpret_cast<const short8*>(&lA[(wr + i * 16 + lr) * LDAB + lg * 8]);
#pragma unroll
    for (int j = 0; j < 4; ++j)
      bfr[j] = *reinterpret_cast<const short8*>(&lB[(wc + j * 16 + lr) * LDAB + lg * 8]);
#pragma unroll
    for (int i = 0; i < 4; ++i)
#pragma unroll
      for (int j = 0; j < 4; ++j)
        acc[i][j] = __builtin_amdgcn_mfma_f32_16x16x32_bf16(af[i], bfr[j], acc[i][j], 0, 0, 0);
    __syncthreads();
  }
#pragma unroll
  for (int i = 0; i < 4; ++i)
#pragma unroll
    for (int j = 0; j < 4; ++j)
#pragma unroll
      for (int ii = 0; ii < 4; ++ii) {
        int r = bm * 128 + wr + i * 16 + lg * 4 + ii;
        int c = bn * 128 + wc + j * 16 + lr;
        float v = acc[i][j][ii] * oscale;
        if (mode == 0) {
          int b = r >> 11, s = r & (S_ - 1), h = c >> 6, dk = c & 63;
          outH[(((size_t)(b * H_ + h) * S_ + s) * DK_) + dk] = f2bf(v);
        } else {
          outF[(size_t)r * N + c] = v;
        }
      }
}

// Vh [B,H,S,DK] -> VhT [B,H,DK,S], 64x64 LDS tiles
__global__ __launch_bounds__(256) void transp_kernel(const unsigned short* __restrict__ Vh,
                                                     unsigned short* __restrict__ VhT) {
  __shared__ unsigned short t[64 * 68];
  const int bh = blockIdx.x >> 5, st = blockIdx.x & 31;
  const size_t base = (size_t)bh * S_ * DK_;
  const int r = threadIdx.x >> 3, e8 = (threadIdx.x & 7) * 8;
#pragma unroll
  for (int h2 = 0; h2 < 2; ++h2) {
    int row = r + h2 * 32;
    *reinterpret_cast<short8*>(&t[row * 68 + e8]) =
        *reinterpret_cast<const short8*>(&Vh[base + (size_t)(st * 64 + row) * DK_ + e8]);
  }
  __syncthreads();
#pragma unroll
  for (int h2 = 0; h2 < 2; ++h2) {
    int dk = (threadIdx.x >> 3) + h2 * 32;
    int sc = (threadIdx.x & 7) * 8;
    short8 v;
#pragma unroll
    for (int j = 0; j < 8; ++j) v[j] = t[(sc + j) * 68 + dk];
    *reinterpret_cast<short8*>(&VhT[base + (size_t)dk * S_ + st * 64 + sc]) = v;
  }
}

// One block = 64 query rows of one (b,h). In-register online softmax.
// Q pre-scaled by 1/8 at projection time.
__global__ __launch_bounds__(256, 4) void attn_kernel(const unsigned short* __restrict__ Qh,
                                                      const unsigned short* __restrict__ Kh,
                                                      const unsigned short* __restrict__ Vh,
                                                      const unsigned short* __restrict__ VhT,
                                                      const float* __restrict__ reaches,
                                                      const float* __restrict__ rsum,
                                                      unsigned short* __restrict__ concat) {
  __shared__ unsigned short lQ[64 * 72];
  __shared__ unsigned short lK[64 * 72];
  __shared__ unsigned short vT[64 * 72];   // vT[d][k] staged from VhT (coalesced)
  __shared__ unsigned short pw[64 * 76];   // weighted probs, wave-private rows
  __shared__ float reachT[64];

  const int tid = threadIdx.x;
  const int qt = blockIdx.x & 31;
  const int bh = blockIdx.x >> 5;
  const int b = bh >> 4, h = bh & 15;
  const size_t base = (size_t)bh * S_ * DK_;

  const int w = tid >> 6, lane = tid & 63;
  const int lr = lane & 15, lg = lane >> 4;
  const int r2 = tid >> 3, e8 = (tid & 7) * 8;

  // stage Q tile
#pragma unroll
  for (int h2 = 0; h2 < 2; ++h2) {
    int row = r2 + h2 * 32;
    *reinterpret_cast<short8*>(&lQ[row * 72 + e8]) =
        *reinterpret_cast<const short8*>(&Qh[base + (size_t)(qt * 64 + row) * DK_ + e8]);
  }

  const int qg0 = qt * 64 + w * 16 + lg * 4;  // q row of acc reg ii = qg0 + ii
  float m_run[4], l_run[4];
  f32x4 acc[4];
#pragma unroll
  for (int ii = 0; ii < 4; ++ii) { m_run[ii] = -1e30f; l_run[ii] = 0.f; }
#pragma unroll
  for (int c4 = 0; c4 < 4; ++c4) acc[c4] = (f32x4){0.f, 0.f, 0.f, 0.f};

  for (int kt = 0; kt < 32; ++kt) {
    // stage K tile + V^T tile (both coalesced short8)
#pragma unroll
    for (int h2 = 0; h2 < 2; ++h2) {
      int row = r2 + h2 * 32;
      *reinterpret_cast<short8*>(&lK[row * 72 + e8]) =
          *reinterpret_cast<const short8*>(&Kh[base + (size_t)(kt * 64 + row) * DK_ + e8]);
      *reinterpret_cast<short8*>(&vT[row * 72 + e8]) =
          *reinterpret_cast<const short8*>(&VhT[base + (size_t)row * S_ + kt * 64 + e8]);
    }
    if (tid < 64) reachT[tid] = reaches[b * S_ + kt * 64 + tid];
    __syncthreads();

    // S = Q K^T (scale folded into Q). C-layout: row q = w*16+lg*4+ii, col k = c4*16+lr
    f32x4 sf[4];
#pragma unroll
    for (int c4 = 0; c4 < 4; ++c4) sf[c4] = (f32x4){0.f, 0.f, 0.f, 0.f};
#pragma unroll
    for (int kk = 0; kk < 2; ++kk) {
      short8 a = *reinterpret_cast<const short8*>(&lQ[(w * 16 + lr) * 72 + kk * 32 + lg * 8]);
#pragma unroll
      for (int c4 = 0; c4 < 4; ++c4) {
        short8 bb = *reinterpret_cast<const short8*>(&lK[(c4 * 16 + lr) * 72 + kk * 32 + lg * 8]);
        sf[c4] = __builtin_amdgcn_mfma_f32_16x16x32_bf16(a, bb, sf[c4], 0, 0, 0);
      }
    }

    // in-register online softmax (row reduce across the 16-lane lr group)
    float mx[4], ps[4], mnew[4], alpha[4];
#pragma unroll
    for (int ii = 0; ii < 4; ++ii)
      mx[ii] = fmaxf(fmaxf(sf[0][ii], sf[1][ii]), fmaxf(sf[2][ii], sf[3][ii]));
#pragma unroll
    for (int o = 1; o <= 8; o <<= 1)
#pragma unroll
      for (int ii = 0; ii < 4; ++ii) mx[ii] = fmaxf(mx[ii], __shfl_xor(mx[ii], o, 64));
#pragma unroll
    for (int ii = 0; ii < 4; ++ii) { mnew[ii] = fmaxf(m_run[ii], mx[ii]); ps[ii] = 0.f; }
#pragma unroll
    for (int c4 = 0; c4 < 4; ++c4)
#pragma unroll
      for (int ii = 0; ii < 4; ++ii) {
        float e = __expf(sf[c4][ii] - mnew[ii]);
        sf[c4][ii] = e;
        ps[ii] += e;
      }
#pragma unroll
    for (int o = 1; o <= 8; o <<= 1)
#pragma unroll
      for (int ii = 0; ii < 4; ++ii) ps[ii] += __shfl_xor(ps[ii], o, 64);
#pragma unroll
    for (int ii = 0; ii < 4; ++ii) {
      alpha[ii] = __expf(m_run[ii] - mnew[ii]);
      l_run[ii] = l_run[ii] * alpha[ii] + ps[ii];
      m_run[ii] = mnew[ii];
    }
#pragma unroll
    for (int c4 = 0; c4 < 4; ++c4)
#pragma unroll
      for (int ii = 0; ii < 4; ++ii) acc[c4][ii] *= alpha[ii];

    // reach-weight + diagonal suppression, write P to wave-private pw rows
#pragma unroll
    for (int c4 = 0; c4 < 4; ++c4) {
      float wb = reachT[c4 * 16 + lr];
      int kg = kt * 64 + c4 * 16 + lr;
#pragma unroll
      for (int ii = 0; ii < 4; ++ii) {
        float wg = wb;
        if (kg == qg0 + ii) wg *= (1.0f - 0.999999f);
        pw[(w * 16 + lg * 4 + ii) * 76 + c4 * 16 + lr] = f2bf(sf[c4][ii] * wg);
      }
    }

    // PV: acc += pw @ V  (pw rows wave-private -> no barrier; ds waits auto)
#pragma unroll
    for (int kk = 0; kk < 2; ++kk) {
      short8 a = *reinterpret_cast<const short8*>(&pw[(w * 16 + lr) * 76 + kk * 32 + lg * 8]);
#pragma unroll
      for (int c4 = 0; c4 < 4; ++c4) {
        short8 bb = *reinterpret_cast<const short8*>(&vT[(c4 * 16 + lr) * 72 + kk * 32 + lg * 8]);
        acc[c4] = __builtin_amdgcn_mfma_f32_16x16x32_bf16(a, bb, acc[c4], 0, 0, 0);
      }
    }
    __syncthreads();  // all waves done with lK/vT before next stage
  }

  // epilogue
  const float rb = rsum[b];
  float contrib[4];
#pragma unroll
  for (int ii = 0; ii < 4; ++ii) {
    float rq = reaches[b * S_ + qg0 + ii];
    contrib[ii] = (rb - rq) / (rb + 1e-9f) * (1.f - rq) * 100.f;
  }
#pragma unroll
  for (int c4 = 0; c4 < 4; ++c4)
#pragma unroll
    for (int ii = 0; ii < 4; ++ii) {
      int qg = qg0 + ii;
      int d = c4 * 16 + lr;
      float pv = acc[c4][ii] / l_run[ii];
      float vhv = bf2f(Vh[base + (size_t)qg * DK_ + d]);
      float o = (vhv - pv) * contrib[ii];
      concat[((size_t)(b * S_ + qg)) * D_ + h * 64 + d] = f2bf(o);
    }
}

extern "C" void kernel_launch(void* const* d_in, const int* in_sizes, int n_in,
                              void* d_out, int out_size, void* d_ws, size_t ws_size,
                              hipStream_t stream) {
  const float* q = (const float*)d_in[0];
  const float* k = (const float*)d_in[1];
  const float* v = (const float*)d_in[2];
  const float* reaches = (const float*)d_in[3];
  const float* Wq = (const float*)d_in[4];
  const float* Wk = (const float*)d_in[5];
  const float* Wv = (const float*)d_in[6];
  const float* Wo = (const float*)d_in[7];

  const size_t NQKV = (size_t)B_ * S_ * D_;   // 4194304
  const size_t NW = (size_t)D_ * D_;          // 1048576

  unsigned short* q_bf = (unsigned short*)d_ws;
  unsigned short* k_bf = q_bf + NQKV;
  unsigned short* v_bf = k_bf + NQKV;
  unsigned short* Wq_bf = v_bf + NQKV;
  unsigned short* Wk_bf = Wq_bf + NW;
  unsigned short* Wv_bf = Wk_bf + NW;
  unsigned short* Wo_bf = Wv_bf + NW;
  unsigned short* Qh = Wo_bf + NW;
  unsigned short* Kh = Qh + NQKV;
  unsigned short* Vh = Kh + NQKV;
  unsigned short* concat = Vh + NQKV;
  float* rs = (float*)(concat + NQKV);
  unsigned short* VhT = q_bf;  // alias: q_bf dead after Q-projection GEMM

  cvt3_kernel<<<dim3(NQKV / 1024, 3), 256, 0, stream>>>(q, k, v, q_bf, k_bf, v_bf);
  cvt4_kernel<<<dim3(NW / 1024, 4), 256, 0, stream>>>(Wq, Wk, Wv, Wo, Wq_bf, Wk_bf, Wv_bf, Wo_bf);
  rs_kernel<<<B_, 256, 0, stream>>>(reaches, rs);

  const int M = B_ * S_;  // 4096
  gemm_bt<<<(M / 128) * (D_ / 128), 256, 0, stream>>>(q_bf, Wq_bf, nullptr, Qh, M, D_, D_, 0, 0.125f);
  gemm_bt<<<(M / 128) * (D_ / 128), 256, 0, stream>>>(k_bf, Wk_bf, nullptr, Kh, M, D_, D_, 0, 1.0f);
  gemm_bt<<<(M / 128) * (D_ / 128), 256, 0, stream>>>(v_bf, Wv_bf, nullptr, Vh, M, D_, D_, 0, 1.0f);
  transp_kernel<<<B_ * H_ * (S_ / 64), 256, 0, stream>>>(Vh, VhT);

  attn_kernel<<<B_ * H_ * (S_ / 64), 256, 0, stream>>>(Qh, Kh, Vh, VhT, reaches, rs, concat);

  gemm_bt<<<(M / 128) * (D_ / 128), 256, 0, stream>>>(concat, Wo_bf, (float*)d_out, nullptr, M, D_, D_, 1, 1.0f);
}

// Round 4
// 169.668 us; speedup vs baseline: 1.9996x; 1.5646x over previous
//
#include <hip/hip_runtime.h>

typedef __attribute__((ext_vector_type(8))) short short8;
typedef __attribute__((ext_vector_type(4))) float f32x4;
typedef unsigned short us;

#define B_ 2
#define S_ 2048
#define D_ 1024
#define H_ 16
#define DK_ 64
#define QSCALE 0.1803368867f  // log2(e) / 8

__device__ __forceinline__ us f2bf(float f) {
  union { float f; unsigned u; } x; x.f = f;
  unsigned r = x.u + 0x7FFFu + ((x.u >> 16) & 1u);
  return (us)(r >> 16);
}
__device__ __forceinline__ float bf2f(us h) {
  union { unsigned u; float f; } x; x.u = ((unsigned)h) << 16;
  return x.f;
}

__device__ __forceinline__ void gload16(const void* g, void* l) {
  __builtin_amdgcn_global_load_lds((const __attribute__((address_space(1))) void*)g,
                                   (__attribute__((address_space(3))) void*)l, 16, 0, 0);
}

__global__ __launch_bounds__(256) void cvt3_kernel(const float* __restrict__ a,
                                                   const float* __restrict__ b,
                                                   const float* __restrict__ c,
                                                   us* __restrict__ oa,
                                                   us* __restrict__ ob,
                                                   us* __restrict__ oc) {
  const float* in; us* out;
  if (blockIdx.y == 0) { in = a; out = oa; }
  else if (blockIdx.y == 1) { in = b; out = ob; }
  else { in = c; out = oc; }
  int i = (blockIdx.x * 256 + threadIdx.x) * 4;
  float4 v = *reinterpret_cast<const float4*>(in + i);
  ushort4 o;
  o.x = f2bf(v.x); o.y = f2bf(v.y); o.z = f2bf(v.z); o.w = f2bf(v.w);
  *reinterpret_cast<ushort4*>(out + i) = o;
}

__global__ __launch_bounds__(256) void cvt4_kernel(const float* __restrict__ a,
                                                   const float* __restrict__ b,
                                                   const float* __restrict__ c,
                                                   const float* __restrict__ d,
                                                   us* __restrict__ oa, us* __restrict__ ob,
                                                   us* __restrict__ oc, us* __restrict__ od) {
  const float* in; us* out;
  if (blockIdx.y == 0) { in = a; out = oa; }
  else if (blockIdx.y == 1) { in = b; out = ob; }
  else if (blockIdx.y == 2) { in = c; out = oc; }
  else { in = d; out = od; }
  int i = (blockIdx.x * 256 + threadIdx.x) * 4;
  float4 v = *reinterpret_cast<const float4*>(in + i);
  ushort4 o;
  o.x = f2bf(v.x); o.y = f2bf(v.y); o.z = f2bf(v.z); o.w = f2bf(v.w);
  *reinterpret_cast<ushort4*>(out + i) = o;
}

__global__ __launch_bounds__(256) void rs_kernel(const float* __restrict__ reaches,
                                                 float* __restrict__ rs) {
  int b = blockIdx.x, t = threadIdx.x;
  float s = 0.f;
  for (int i = t; i < S_; i += 256) s += reaches[b * S_ + i];
  for (int o = 32; o > 0; o >>= 1) s += __shfl_down(s, o, 64);
  __shared__ float tmp[4];
  if ((t & 63) == 0) tmp[t >> 6] = s;
  __syncthreads();
  if (t == 0) rs[b] = tmp[0] + tmp[1] + tmp[2] + tmp[3];
}

// m97-structure GEMM core: 128x128 tile, BK=32, linear LDS + global_load_lds w16.
// All GEMMs here are M=4096, N=1024, K=1024, A row-major, Bt row-major (B^T).
template <int MODE>  // 0: bf16 head-split [B,H,S,DK]; 1: fp32 row-major
__device__ __forceinline__ void gemm_core(const us* __restrict__ A, const us* __restrict__ Bt,
                                          float* __restrict__ outF, us* __restrict__ outH,
                                          float oscale) {
  __shared__ __align__(16) us lA[128 * 32];
  __shared__ __align__(16) us lB[128 * 32];
  const int tid = threadIdx.x;
  const int bm = blockIdx.x >> 3, bn = blockIdx.x & 7;
  const int w = tid >> 6, lane = tid & 63;
  const int wr = (w >> 1) * 64, wc = (w & 1) * 64;
  const int lr = lane & 15, lg = lane >> 4;

  f32x4 acc[4][4];
#pragma unroll
  for (int i = 0; i < 4; ++i)
#pragma unroll
    for (int j = 0; j < 4; ++j) acc[i][j] = (f32x4){0.f, 0.f, 0.f, 0.f};

  // wave w stages chunks {2w,2w+1}: chunk c -> LDS elems [c*512,+512) = rows [c*16,+16)
  const int crow = lane >> 2, ce8 = (lane & 3) * 8;
  const us* A0 = A + (size_t)(bm * 128 + w * 32 + crow) * 1024 + ce8;
  const us* A1 = A + (size_t)(bm * 128 + w * 32 + 16 + crow) * 1024 + ce8;
  const us* B0 = Bt + (size_t)(bn * 128 + w * 32 + crow) * 1024 + ce8;
  const us* B1 = Bt + (size_t)(bn * 128 + w * 32 + 16 + crow) * 1024 + ce8;
  us* lA0 = &lA[(w * 2) * 512]; us* lA1 = &lA[(w * 2 + 1) * 512];
  us* lB0 = &lB[(w * 2) * 512]; us* lB1 = &lB[(w * 2 + 1) * 512];

  for (int kt = 0; kt < 1024; kt += 32) {
    gload16(A0 + kt, lA0);
    gload16(A1 + kt, lA1);
    gload16(B0 + kt, lB0);
    gload16(B1 + kt, lB1);
    __syncthreads();  // drains vmcnt (global_load_lds) before reads
    short8 af[4], bfr[4];
#pragma unroll
    for (int i = 0; i < 4; ++i)
      af[i] = *reinterpret_cast<const short8*>(&lA[(wr + i * 16 + lr) * 32 + lg * 8]);
#pragma unroll
    for (int j = 0; j < 4; ++j)
      bfr[j] = *reinterpret_cast<const short8*>(&lB[(wc + j * 16 + lr) * 32 + lg * 8]);
#pragma unroll
    for (int i = 0; i < 4; ++i)
#pragma unroll
      for (int j = 0; j < 4; ++j)
        acc[i][j] = __builtin_amdgcn_mfma_f32_16x16x32_bf16(af[i], bfr[j], acc[i][j], 0, 0, 0);
    __syncthreads();  // all reads done before next-tile gload overwrites
  }
#pragma unroll
  for (int i = 0; i < 4; ++i)
#pragma unroll
    for (int j = 0; j < 4; ++j)
#pragma unroll
      for (int ii = 0; ii < 4; ++ii) {
        int r = bm * 128 + wr + i * 16 + lg * 4 + ii;
        int c = bn * 128 + wc + j * 16 + lr;
        float v = acc[i][j][ii] * oscale;
        if (MODE == 0) {
          int b = r >> 11, s = r & (S_ - 1), h = c >> 6, dk = c & 63;
          outH[(((size_t)(b * H_ + h) * S_ + s) * DK_) + dk] = f2bf(v);
        } else {
          outF[(size_t)r * 1024 + c] = v;
        }
      }
}

__global__ __launch_bounds__(256) void proj_gemm(const us* __restrict__ q_bf,
                                                 const us* __restrict__ k_bf,
                                                 const us* __restrict__ v_bf,
                                                 const us* __restrict__ Wq_bf,
                                                 const us* __restrict__ Wk_bf,
                                                 const us* __restrict__ Wv_bf,
                                                 us* __restrict__ Qh, us* __restrict__ Kh,
                                                 us* __restrict__ Vh) {
  if (blockIdx.y == 0) gemm_core<0>(q_bf, Wq_bf, nullptr, Qh, QSCALE);
  else if (blockIdx.y == 1) gemm_core<0>(k_bf, Wk_bf, nullptr, Kh, 1.0f);
  else gemm_core<0>(v_bf, Wv_bf, nullptr, Vh, 1.0f);
}

__global__ __launch_bounds__(256) void wo_gemm(const us* __restrict__ concat,
                                               const us* __restrict__ Wo_bf,
                                               float* __restrict__ out) {
  gemm_core<1>(concat, Wo_bf, out, nullptr, 1.0f);
}

// Vh [B,H,S,DK] -> VhT [B,H,DK,S]
__global__ __launch_bounds__(256) void transp_kernel(const us* __restrict__ Vh,
                                                     us* __restrict__ VhT) {
  __shared__ us t[64 * 68];
  const int bh = blockIdx.x >> 5, st = blockIdx.x & 31;
  const size_t base = (size_t)bh * S_ * DK_;
  const int r = threadIdx.x >> 3, e8 = (threadIdx.x & 7) * 8;
#pragma unroll
  for (int h2 = 0; h2 < 2; ++h2) {
    int row = r + h2 * 32;
    *reinterpret_cast<short8*>(&t[row * 68 + e8]) =
        *reinterpret_cast<const short8*>(&Vh[base + (size_t)(st * 64 + row) * DK_ + e8]);
  }
  __syncthreads();
#pragma unroll
  for (int h2 = 0; h2 < 2; ++h2) {
    int dk = (threadIdx.x >> 3) + h2 * 32;
    int sc = (threadIdx.x & 7) * 8;
    short8 v;
#pragma unroll
    for (int j = 0; j < 8; ++j) v[j] = t[(sc + j) * 68 + dk];
    *reinterpret_cast<short8*>(&VhT[base + (size_t)dk * S_ + st * 64 + sc]) = v;
  }
}

// Max-free streaming softmax attention. Q pre-scaled by log2(e)/8.
__global__ __launch_bounds__(256, 4) void attn_kernel(const us* __restrict__ Qh,
                                                      const us* __restrict__ Kh,
                                                      const us* __restrict__ Vh,
                                                      const us* __restrict__ VhT,
                                                      const float* __restrict__ reaches,
                                                      const float* __restrict__ rsum,
                                                      us* __restrict__ concat) {
  __shared__ __align__(16) us lQ[64 * 72];
  __shared__ __align__(16) us lK[64 * 72];
  __shared__ __align__(16) us vT[64 * 72];
  __shared__ __align__(16) us pw[64 * 76];

  const int tid = threadIdx.x;
  const int bid = ((blockIdx.x & 7) << 7) | (blockIdx.x >> 3);  // XCD-chunked swizzle (1024%8==0)
  const int qt = bid & 31;
  const int bh = bid >> 5;
  const int b = bh >> 4, h = bh & 15;
  const size_t base = (size_t)bh * S_ * DK_;

  const int w = tid >> 6, lane = tid & 63;
  const int lr = lane & 15, lg = lane >> 4;
  const int r2 = tid >> 3, e8 = (tid & 7) * 8;

  // stage Q
#pragma unroll
  for (int h2 = 0; h2 < 2; ++h2) {
    int row = r2 + h2 * 32;
    *reinterpret_cast<short8*>(&lQ[row * 72 + e8]) =
        *reinterpret_cast<const short8*>(&Qh[base + (size_t)(qt * 64 + row) * DK_ + e8]);
  }

  // prefetch regs (T14 async-stage split)
  short8 pk0, pk1, pv0, pv1;
  pk0 = *reinterpret_cast<const short8*>(&Kh[base + (size_t)r2 * DK_ + e8]);
  pk1 = *reinterpret_cast<const short8*>(&Kh[base + (size_t)(r2 + 32) * DK_ + e8]);
  pv0 = *reinterpret_cast<const short8*>(&VhT[base + (size_t)r2 * S_ + e8]);
  pv1 = *reinterpret_cast<const short8*>(&VhT[base + (size_t)(r2 + 32) * S_ + e8]);
  *reinterpret_cast<short8*>(&lK[r2 * 72 + e8]) = pk0;
  *reinterpret_cast<short8*>(&lK[(r2 + 32) * 72 + e8]) = pk1;
  *reinterpret_cast<short8*>(&vT[r2 * 72 + e8]) = pv0;
  *reinterpret_cast<short8*>(&vT[(r2 + 32) * 72 + e8]) = pv1;
  __syncthreads();

  const int qg0 = qt * 64 + w * 16 + lg * 4;  // q row of acc reg ii = qg0+ii
  f32x4 acc[4];
  float lacc[4] = {0.f, 0.f, 0.f, 0.f};
#pragma unroll
  for (int c4 = 0; c4 < 4; ++c4) acc[c4] = (f32x4){0.f, 0.f, 0.f, 0.f};

  for (int kt = 0; kt < 32; ++kt) {
    if (kt < 31) {  // issue next-tile loads; consumed after the barrier
      int nt = kt + 1;
      pk0 = *reinterpret_cast<const short8*>(&Kh[base + (size_t)(nt * 64 + r2) * DK_ + e8]);
      pk1 = *reinterpret_cast<const short8*>(&Kh[base + (size_t)(nt * 64 + r2 + 32) * DK_ + e8]);
      pv0 = *reinterpret_cast<const short8*>(&VhT[base + (size_t)r2 * S_ + nt * 64 + e8]);
      pv1 = *reinterpret_cast<const short8*>(&VhT[base + (size_t)(r2 + 32) * S_ + nt * 64 + e8]);
    }
    float rwc[4];
#pragma unroll
    for (int c4 = 0; c4 < 4; ++c4) rwc[c4] = reaches[b * S_ + kt * 64 + c4 * 16 + lr];

    // S' = Q K^T * log2e/8 (folded into Q)
    f32x4 sf[4];
#pragma unroll
    for (int c4 = 0; c4 < 4; ++c4) sf[c4] = (f32x4){0.f, 0.f, 0.f, 0.f};
#pragma unroll
    for (int kk = 0; kk < 2; ++kk) {
      short8 a = *reinterpret_cast<const short8*>(&lQ[(w * 16 + lr) * 72 + kk * 32 + lg * 8]);
#pragma unroll
      for (int c4 = 0; c4 < 4; ++c4) {
        short8 bb = *reinterpret_cast<const short8*>(&lK[(c4 * 16 + lr) * 72 + kk * 32 + lg * 8]);
        sf[c4] = __builtin_amdgcn_mfma_f32_16x16x32_bf16(a, bb, sf[c4], 0, 0, 0);
      }
    }

    // streaming (max-free) softmax: P = 2^S', accumulate l, weight, write pw
    if (kt == qt) {  // uniform branch: diagonal lives in this tile only
#pragma unroll
      for (int c4 = 0; c4 < 4; ++c4) {
#pragma unroll
        for (int ii = 0; ii < 4; ++ii) {
          float e = __builtin_amdgcn_exp2f(sf[c4][ii]);
          lacc[ii] += e;
          float wg = rwc[c4];
          if (c4 * 16 + lr == w * 16 + lg * 4 + ii) wg *= (1.0f - 0.999999f);
          pw[(w * 16 + lg * 4 + ii) * 76 + c4 * 16 + lr] = f2bf(e * wg);
        }
      }
    } else {
#pragma unroll
      for (int c4 = 0; c4 < 4; ++c4) {
#pragma unroll
        for (int ii = 0; ii < 4; ++ii) {
          float e = __builtin_amdgcn_exp2f(sf[c4][ii]);
          lacc[ii] += e;
          pw[(w * 16 + lg * 4 + ii) * 76 + c4 * 16 + lr] = f2bf(e * rwc[c4]);
        }
      }
    }

    // PV: acc += pw @ V  (pw rows wave-private; compiler inserts lgkm waits)
#pragma unroll
    for (int kk = 0; kk < 2; ++kk) {
      short8 a = *reinterpret_cast<const short8*>(&pw[(w * 16 + lr) * 76 + kk * 32 + lg * 8]);
#pragma unroll
      for (int c4 = 0; c4 < 4; ++c4) {
        short8 bb = *reinterpret_cast<const short8*>(&vT[(c4 * 16 + lr) * 72 + kk * 32 + lg * 8]);
        acc[c4] = __builtin_amdgcn_mfma_f32_16x16x32_bf16(a, bb, acc[c4], 0, 0, 0);
      }
    }
    __syncthreads();  // all waves done reading lK/vT
    if (kt < 31) {    // write prefetched next tile (vmcnt wait auto-inserted)
      *reinterpret_cast<short8*>(&lK[r2 * 72 + e8]) = pk0;
      *reinterpret_cast<short8*>(&lK[(r2 + 32) * 72 + e8]) = pk1;
      *reinterpret_cast<short8*>(&vT[r2 * 72 + e8]) = pv0;
      *reinterpret_cast<short8*>(&vT[(r2 + 32) * 72 + e8]) = pv1;
    }
    __syncthreads();
  }

  // deferred l reduction across the 16-lane lr group
#pragma unroll
  for (int o = 1; o <= 8; o <<= 1)
#pragma unroll
    for (int ii = 0; ii < 4; ++ii) lacc[ii] += __shfl_xor(lacc[ii], o, 64);

  const float rb = rsum[b];
  float contrib[4];
#pragma unroll
  for (int ii = 0; ii < 4; ++ii) {
    float rq = reaches[b * S_ + qg0 + ii];
    contrib[ii] = (rb - rq) / (rb + 1e-9f) * (1.f - rq) * 100.f;
  }
#pragma unroll
  for (int c4 = 0; c4 < 4; ++c4)
#pragma unroll
    for (int ii = 0; ii < 4; ++ii) {
      int qg = qg0 + ii;
      int d = c4 * 16 + lr;
      float pv = acc[c4][ii] / lacc[ii];
      float vhv = bf2f(Vh[base + (size_t)qg * DK_ + d]);
      float o = (vhv - pv) * contrib[ii];
      concat[((size_t)(b * S_ + qg)) * D_ + h * 64 + d] = f2bf(o);
    }
}

extern "C" void kernel_launch(void* const* d_in, const int* in_sizes, int n_in,
                              void* d_out, int out_size, void* d_ws, size_t ws_size,
                              hipStream_t stream) {
  const float* q = (const float*)d_in[0];
  const float* k = (const float*)d_in[1];
  const float* v = (const float*)d_in[2];
  const float* reaches = (const float*)d_in[3];
  const float* Wq = (const float*)d_in[4];
  const float* Wk = (const float*)d_in[5];
  const float* Wv = (const float*)d_in[6];
  const float* Wo = (const float*)d_in[7];

  const size_t NQKV = (size_t)B_ * S_ * D_;
  const size_t NW = (size_t)D_ * D_;

  us* q_bf = (us*)d_ws;
  us* k_bf = q_bf + NQKV;
  us* v_bf = k_bf + NQKV;
  us* Wq_bf = v_bf + NQKV;
  us* Wk_bf = Wq_bf + NW;
  us* Wv_bf = Wk_bf + NW;
  us* Wo_bf = Wv_bf + NW;
  us* Qh = Wo_bf + NW;
  us* Kh = Qh + NQKV;
  us* Vh = Kh + NQKV;
  us* concat = Vh + NQKV;
  float* rs = (float*)(concat + NQKV);
  us* VhT = q_bf;  // alias: q_bf dead after proj_gemm

  cvt3_kernel<<<dim3(NQKV / 1024, 3), 256, 0, stream>>>(q, k, v, q_bf, k_bf, v_bf);
  cvt4_kernel<<<dim3(NW / 1024, 4), 256, 0, stream>>>(Wq, Wk, Wv, Wo, Wq_bf, Wk_bf, Wv_bf, Wo_bf);
  rs_kernel<<<B_, 256, 0, stream>>>(reaches, rs);

  proj_gemm<<<dim3(256, 3), 256, 0, stream>>>(q_bf, k_bf, v_bf, Wq_bf, Wk_bf, Wv_bf, Qh, Kh, Vh);
  transp_kernel<<<B_ * H_ * (S_ / 64), 256, 0, stream>>>(Vh, VhT);

  attn_kernel<<<B_ * H_ * (S_ / 64), 256, 0, stream>>>(Qh, Kh, Vh, VhT, reaches, rs, concat);

  wo_gemm<<<256, 256, 0, stream>>>(concat, Wo_bf, (float*)d_out);
}